// Round 6
// baseline (387.644 us; speedup 1.0000x reference)
//
#include <hip/hip_runtime.h>
#include <math.h>

// (B, N, IN, OUT, H, F) = (4, 2048, 128, 64, 4, 64)
#define BB   4
#define NN   2048
#define IND  128
#define CDIM 256          // H*OUT
#define NIT  16           // j-iterations of 128

typedef _Float16 half_t;
typedef _Float16 half4_t __attribute__((ext_vector_type(4)));
typedef _Float16 half8_t __attribute__((ext_vector_type(8)));
typedef float    f32x4   __attribute__((ext_vector_type(4)));

#define SHIFT 16.0f            // fixed softmax shift (S range ~[-24,24])
#define BSCL  6.103515625e-05f // 1/16384: u16 fixed-point step for fused bias
#define BOFF  (-17.5f)         // -1.5 (encode offset) - SHIFT

// ---------------------------------------------------------------------------
// WhJ layout v2 (frag-pair-packed): per (b, j16) tile of 4096 halves,
// element (j, c):  addr = (c>>5)*512 + (c&15)*32 + (j>>2)*8 + ((c>>4)&1)*4 + (j&3)
// -> PV lane (n,q) of wave w reads its TWO B-frags (cols w*32+n, w*32+16+n)
//    as ONE contiguous half8 at  w*512 + n*32 + q*8.  (16 loads -> 8)
// ---------------------------------------------------------------------------

// ---------------------------------------------------------------------------
// Kernel A: per-row features -> f16 Q, K (row-major) and WhJ v2 tiles.
// ---------------------------------------------------------------------------
__global__ __launch_bounds__(256) void precompute_kernel(
    const float* __restrict__ hg,   // (B*N, 128)
    const float* __restrict__ W,    // (128, 256)
    const float* __restrict__ R,    // (128, 64)
    const float* __restrict__ aq,   // (128, 64)
    const float* __restrict__ ak,   // (128, 64)
    half_t* __restrict__ Qw,        // (B*N, 64) f16
    half_t* __restrict__ Kw,        // (B*N, 64) f16
    half_t* __restrict__ WhJ)       // (B, 128, 4096) f16 v2-tiled
{
    const int tid  = threadIdx.x;
    const int row0 = blockIdx.x * 8;

    __shared__ float hs[8][IND];
    __shared__ float phis[8][IND];

    {   // 8 rows x 128 = 256 float4
        const float4* src = (const float4*)(hg + (size_t)row0 * IND);
        ((float4*)&hs[0][0])[tid] = src[tid];
    }
    __syncthreads();

    {   // phi: f = tid&63, rr = tid>>6 in 0..3 -> rows rr, rr+4
        const int f  = tid & 63;
        const int rr = tid >> 6;
        float p0 = 0.f, p1 = 0.f;
        #pragma unroll 4
        for (int d0 = 0; d0 < IND; d0 += 4) {
            const float r0 = R[(d0 + 0) * 64 + f];
            const float r1 = R[(d0 + 1) * 64 + f];
            const float r2 = R[(d0 + 2) * 64 + f];
            const float r3 = R[(d0 + 3) * 64 + f];
            const float4 ha = *(const float4*)&hs[rr][d0];
            const float4 hb = *(const float4*)&hs[rr + 4][d0];
            p0 += ha.x * r0 + ha.y * r1 + ha.z * r2 + ha.w * r3;
            p1 += hb.x * r0 + hb.y * r1 + hb.z * r2 + hb.w * r3;
        }
        float s, c;
        __sincosf(p0, &s, &c); phis[rr][f]     = c; phis[rr][f + 64]     = s;
        __sincosf(p1, &s, &c); phis[rr + 4][f] = c; phis[rr + 4][f + 64] = s;
    }

    {   // Wh: thread owns column c = tid for the 8-row tile; store v2 layout.
        float acc[8];
        #pragma unroll
        for (int r = 0; r < 8; ++r) acc[r] = 0.f;
        #pragma unroll 2
        for (int d0 = 0; d0 < IND; d0 += 4) {
            const float w0 = W[(d0 + 0) * CDIM + tid];
            const float w1 = W[(d0 + 1) * CDIM + tid];
            const float w2 = W[(d0 + 2) * CDIM + tid];
            const float w3 = W[(d0 + 3) * CDIM + tid];
            #pragma unroll
            for (int r = 0; r < 8; ++r) {
                const float4 h4 = *(const float4*)&hs[r][d0];
                acc[r] += h4.x * w0 + h4.y * w1 + h4.z * w2 + h4.w * w3;
            }
        }
        const int b   = row0 >> 11;
        const int j16 = (row0 & (NN - 1)) >> 4;
        const int jr0 = row0 & 15;                 // 0 or 8 within the 16-tile
        const int fp  = tid >> 5;
        const int hi  = (tid >> 4) & 1;
        const int nn2 = tid & 15;
        half_t* tb = WhJ + ((size_t)(b * 128 + j16)) * 4096
                   + fp * 512 + nn2 * 32 + hi * 4;
        #pragma unroll
        for (int rh = 0; rh < 2; ++rh) {
            const int qv = (jr0 >> 2) + rh;        // j>>2 for this half
            half4_t v;
            #pragma unroll
            for (int k = 0; k < 4; ++k) v[k] = (half_t)acc[rh * 4 + k];
            *(half4_t*)(tb + qv * 8) = v;
        }
    }
    __syncthreads();

    {   // Q/K: o = tid&63, qk bit selects aq/ak, rh = tid>>7 -> rows rh*4..+3
        const int o  = tid & 63;
        const int qk = (tid >> 6) & 1;
        const int rh = tid >> 7;
        const float* A = qk ? ak : aq;
        half_t*    Dst = qk ? Kw : Qw;
        float acc[4] = {0.f, 0.f, 0.f, 0.f};
        #pragma unroll 2
        for (int t0 = 0; t0 < IND; t0 += 4) {
            const float a0 = A[(t0 + 0) * 64 + o];
            const float a1 = A[(t0 + 1) * 64 + o];
            const float a2 = A[(t0 + 2) * 64 + o];
            const float a3 = A[(t0 + 3) * 64 + o];
            #pragma unroll
            for (int r = 0; r < 4; ++r) {
                const float4 ph = *(const float4*)&phis[rh * 4 + r][t0];
                acc[r] += ph.x * a0 + ph.y * a1 + ph.z * a2 + ph.w * a3;
            }
        }
        #pragma unroll
        for (int r = 0; r < 4; ++r)
            Dst[(size_t)(row0 + rh * 4 + r) * 64 + o] = (half_t)acc[r];
    }
}

// ---------------------------------------------------------------------------
// Kernel F: standalone fused-bias stream  bf = q16(pm + sm + qb)  (B,N,N) u16.
// Exact-fit grid (2048x256, 8 quads/thread), 2-deep software pipeline,
// __launch_bounds__(256,4) = 128-VGPR budget -> no spills (R5's failure mode).
// All four streams swept linearly chip-wide (unit-stride per instruction).
// ---------------------------------------------------------------------------
__global__ __launch_bounds__(256, 4) void fuse_bias_kernel(
    const float* __restrict__ pm, const float* __restrict__ sm,
    const int*   __restrict__ qm, const float* __restrict__ qbias,
    unsigned short* __restrict__ bf)
{
    __shared__ float qbs[16];
    if (threadIdx.x < 16) qbs[threadIdx.x] = qbias[threadIdx.x];
    __syncthreads();

    const int stride = 2048 * 256;                // threads in grid
    int idx = blockIdx.x * 256 + threadIdx.x;     // quad index

    float4 pA = ((const float4*)pm)[idx];
    float4 sA = ((const float4*)sm)[idx];
    int4   qA0 = ((const int4*)qm)[(size_t)idx * 2];
    int4   qA1 = ((const int4*)qm)[(size_t)idx * 2 + 1];

    #pragma unroll
    for (int i = 0; i < 8; ++i) {                 // 4,194,304 / 524,288 = 8
        const int nidx = idx + stride;
        float4 pB, sB; int4 qB0, qB1;
        if (i + 1 < 8) {
            pB  = ((const float4*)pm)[nidx];
            sB  = ((const float4*)sm)[nidx];
            qB0 = ((const int4*)qm)[(size_t)nidx * 2];
            qB1 = ((const int4*)qm)[(size_t)nidx * 2 + 1];
        }
        const float f0 = pA.x + sA.x + qbs[(qA0.x << 2) | qA0.y];
        const float f1 = pA.y + sA.y + qbs[(qA0.z << 2) | qA0.w];
        const float f2 = pA.z + sA.z + qbs[(qA1.x << 2) | qA1.y];
        const float f3 = pA.w + sA.w + qbs[(qA1.z << 2) | qA1.w];
        const unsigned u0 = __float2uint_rn(fminf(fmaxf((f0 + 1.5f) * 16384.f, 0.f), 65535.f));
        const unsigned u1 = __float2uint_rn(fminf(fmaxf((f1 + 1.5f) * 16384.f, 0.f), 65535.f));
        const unsigned u2 = __float2uint_rn(fminf(fmaxf((f2 + 1.5f) * 16384.f, 0.f), 65535.f));
        const unsigned u3 = __float2uint_rn(fminf(fmaxf((f3 + 1.5f) * 16384.f, 0.f), 65535.f));
        uint2 o; o.x = u0 | (u1 << 16); o.y = u2 | (u3 << 16);
        ((uint2*)bf)[idx] = o;
        idx = nidx; pA = pB; sA = sB; qA0 = qB0; qA1 = qB1;
    }
}

// ---------------------------------------------------------------------------
// Kernel B (attn7): c-split flash attention, slim L3-resident bias.
//  - bias: ONE uint2/lane/iter from bf (33 MB, just written -> L3-hot),
//    prefetched 4-deep (8 VGPRs total)
//  - PV B-frags: 8x half8 loads/iter (WhJ v2 layout), was 16x half4
//  - K-frags: 1-deep ping-pong
//  - P exchange via LDS + raw s_barrier/lgkmcnt (verified R2/R4)
// ---------------------------------------------------------------------------
#define ITER7(IT, KC0, KC1, KN0, KN1, UB, PB)                                   \
  {                                                                             \
    /* PV B-frag pairs: 8 contiguous half8 loads, consume after barrier */      \
    half8_t bwv[8];                                                             \
    _Pragma("unroll")                                                           \
    for (int kq = 0; kq < 8; ++kq)                                              \
      bwv[kq] = *(const half8_t*)(wb + (size_t)((IT) * 8 + kq) * 4096);         \
    /* scores (transposed): S^T via A=K, B=Q */                                 \
    f32x4 s4 = (f32x4){0.f, 0.f, 0.f, 0.f};                                     \
    s4 = __builtin_amdgcn_mfma_f32_16x16x32_f16(KC0, qf0, s4, 0, 0, 0);         \
    s4 = __builtin_amdgcn_mfma_f32_16x16x32_f16(KC1, qf1, s4, 0, 0, 0);         \
    if ((IT) + 1 < NIT) {                                                       \
      const half_t* kp = kbase + (size_t)((IT) + 1) * 128 * 64;                 \
      KN0 = *(const half8_t*)(kp + q * 8);                                      \
      KN1 = *(const half8_t*)(kp + 32 + q * 8);                                 \
    }                                                                           \
    const uint2 uc = UB;                                                        \
    if ((IT) + 4 < NIT)                                                         \
      UB = *(const uint2*)(bfr + (size_t)((IT) + 4) * 128 + cbase);             \
    const float sv0 = s4[0] + fmaf((float)(uc.x & 0xffffu), BSCL, BOFF);        \
    const float sv1 = s4[1] + fmaf((float)(uc.x >> 16),     BSCL, BOFF);        \
    const float sv2 = s4[2] + fmaf((float)(uc.y & 0xffffu), BSCL, BOFF);        \
    const float sv3 = s4[3] + fmaf((float)(uc.y >> 16),     BSCL, BOFF);        \
    const half_t h0 = (half_t)__expf(fminf(sv0, 11.f));                         \
    const half_t h1 = (half_t)__expf(fminf(sv1, 11.f));                         \
    const half_t h2 = (half_t)__expf(fminf(sv2, 11.f));                         \
    const half_t h3 = (half_t)__expf(fminf(sv3, 11.f));                         \
    half4_t aP; aP[0] = h0; aP[1] = h1; aP[2] = h2; aP[3] = h3;                 \
    lacc += (float)h0 + (float)h1 + (float)h2 + (float)h3;                      \
    *(half4_t*)&Pl[PB][w][lane * 4] = aP;                                       \
    asm volatile("s_waitcnt lgkmcnt(0)" ::: "memory");                          \
    __builtin_amdgcn_s_barrier();                                               \
    asm volatile("" ::: "memory");                                              \
    /* PV: O[i][c] for this wave's 32 cols, k over all 8 stripes */             \
    _Pragma("unroll")                                                           \
    for (int kq = 0; kq < 8; ++kq) {                                            \
      const half4_t pa = *(const half4_t*)&Pl[PB][kq][lane * 4];                \
      half4_t blo, bhi;                                                         \
      blo[0] = bwv[kq][0]; blo[1] = bwv[kq][1];                                 \
      blo[2] = bwv[kq][2]; blo[3] = bwv[kq][3];                                 \
      bhi[0] = bwv[kq][4]; bhi[1] = bwv[kq][5];                                 \
      bhi[2] = bwv[kq][6]; bhi[3] = bwv[kq][7];                                 \
      acc0 = __builtin_amdgcn_mfma_f32_16x16x16f16(pa, blo, acc0, 0, 0, 0);     \
      acc1 = __builtin_amdgcn_mfma_f32_16x16x16f16(pa, bhi, acc1, 0, 0, 0);     \
    }                                                                           \
  }

__global__ __launch_bounds__(512, 4) void attn7_kernel(
    const half_t* __restrict__ Qw, const half_t* __restrict__ Kw,
    const half_t* __restrict__ WhJ,
    const unsigned short* __restrict__ bf,   // (B,N,N) fused bias u16
    const float* __restrict__ op,            // (256,64) f32
    float* __restrict__ out)                 // (B*N, 64)
{
    const int tid  = threadIdx.x;
    const int w    = tid >> 6;         // j-stripe for QK, 32-col slice for PV
    const int lane = tid & 63;
    const int n    = lane & 15;
    const int q    = lane >> 4;

    const int blk = blockIdx.x;
    const int b   = (blk & 7) >> 1;    // XCD swizzle: one batch per XCD pair
    const int i0  = (((blk >> 3) << 1) | (blk & 1)) * 16;

    __shared__ __align__(16) half_t Pl[2][8][256];   // [buf][stripe][lane*4]
    __shared__ __align__(16) float  BufT0[CDIM][20]; // O, transposed [c][row]
    __shared__ float Lp[8][16];

    // persistent Q B-frag: B[k][n] = Q[i0+n][k]
    const half_t* qptr = Qw + ((size_t)(b * NN) + i0 + n) * 64;
    const half8_t qf0 = *(const half8_t*)(qptr + q * 8);
    const half8_t qf1 = *(const half8_t*)(qptr + 32 + q * 8);

    // fused bias: row i = i0+n, cols j = it*128 + w*16 + q*4 + r
    const size_t rowoff = ((size_t)b * NN + i0 + n) * NN;
    const unsigned short* bfr = bf + rowoff;
    const int cbase = w * 16 + q * 4;

    // K A-frag base: A[m=jr][k] = K[it*128 + w*16 + n][k]
    const half_t* kbase = Kw + ((size_t)b * NN + w * 16 + n) * 64;
    // PV B-frag base (v2 layout): wave w pair-block, lane (n,q)
    const half_t* wb = WhJ + (size_t)b * 128 * 4096 + w * 512 + n * 32 + q * 8;

    // prologue prefetch: bias 4-deep, K 1-deep ping-pong
    uint2 ub0 = *(const uint2*)(bfr + cbase);
    uint2 ub1 = *(const uint2*)(bfr + 128 + cbase);
    uint2 ub2 = *(const uint2*)(bfr + 256 + cbase);
    uint2 ub3 = *(const uint2*)(bfr + 384 + cbase);
    half8_t ka0 = *(const half8_t*)(kbase + q * 8);
    half8_t ka1 = *(const half8_t*)(kbase + 32 + q * 8);
    half8_t kb0 = ka0, kb1 = ka1;

    f32x4 acc0 = (f32x4){0.f, 0.f, 0.f, 0.f};
    f32x4 acc1 = (f32x4){0.f, 0.f, 0.f, 0.f};
    float lacc = 0.f;

    for (int it = 0; it < NIT; it += 4) {
        ITER7(it,     ka0, ka1, kb0, kb1, ub0, 0)
        ITER7(it + 1, kb0, kb1, ka0, ka1, ub1, 1)
        ITER7(it + 2, ka0, ka1, kb0, kb1, ub2, 0)
        ITER7(it + 3, kb0, kb1, ka0, ka1, ub3, 1)
    }

    // ---- row-l partials ----
    lacc += __shfl_xor(lacc, 16);
    lacc += __shfl_xor(lacc, 32);
    if (lane < 16) Lp[w][lane] = lacc;

    // ---- each wave stores its own final 32 columns ----
    *(f32x4*)&BufT0[w * 32 + n][q * 4]      = acc0;
    *(f32x4*)&BufT0[w * 32 + 16 + n][q * 4] = acc1;
    __syncthreads();

    // ---- projection + ELU: wave w -> rows 2w, 2w+1 ; lane -> col o ----
    {
        const int r0 = 2 * w, r1 = 2 * w + 1;
        float pacc0 = 0.f, pacc1 = 0.f;
        #pragma unroll 8
        for (int c = 0; c < CDIM; ++c) {
            const float wv = op[c * 64 + lane];     // coalesced, L2-resident
            pacc0 += BufT0[c][r0] * wv;             // LDS broadcast
            pacc1 += BufT0[c][r1] * wv;
        }
        float lt0 = 0.f, lt1 = 0.f;
        #pragma unroll
        for (int gg = 0; gg < 8; ++gg) { lt0 += Lp[gg][r0]; lt1 += Lp[gg][r1]; }
        float x0 = pacc0 / lt0;
        float x1 = pacc1 / lt1;
        x0 = x0 > 0.f ? x0 : (__expf(x0) - 1.f);
        x1 = x1 > 0.f ? x1 : (__expf(x1) - 1.f);
        out[((size_t)b * NN + i0 + r0) * 64 + lane] = x0;
        out[((size_t)b * NN + i0 + r1) * 64 + lane] = x1;
    }
}

// ---------------------------------------------------------------------------
// Fallback: full-bias attn (R2-verified structure, WhJ v2 loads) if the
// workspace can't hold bf.
// ---------------------------------------------------------------------------
__global__ __launch_bounds__(512, 4) void attn7f_kernel(
    const half_t* __restrict__ Qw, const half_t* __restrict__ Kw,
    const half_t* __restrict__ WhJ,
    const float* __restrict__ pm, const float* __restrict__ sm,
    const int*   __restrict__ qm, const float* __restrict__ qbias,
    const float* __restrict__ op, float* __restrict__ out)
{
    const int tid  = threadIdx.x;
    const int w    = tid >> 6;
    const int lane = tid & 63;
    const int n    = lane & 15;
    const int q    = lane >> 4;

    const int blk = blockIdx.x;
    const int b   = (blk & 7) >> 1;
    const int i0  = (((blk >> 3) << 1) | (blk & 1)) * 16;

    __shared__ __align__(16) half_t Pl[2][8][256];
    __shared__ __align__(16) float  BufT0[CDIM][20];
    __shared__ float Lp[8][16];
    __shared__ float qbs[16];

    if (tid < 16) qbs[tid] = qbias[tid] - SHIFT;
    __syncthreads();

    const half_t* qptr = Qw + ((size_t)(b * NN) + i0 + n) * 64;
    const half8_t qf0 = *(const half8_t*)(qptr + q * 8);
    const half8_t qf1 = *(const half8_t*)(qptr + 32 + q * 8);

    const size_t rowoff = ((size_t)b * NN + i0 + n) * NN;
    const float* pmr = pm + rowoff;
    const float* smr = sm + rowoff;
    const int*   qmr = qm + rowoff * 2;
    const int cbase = w * 16 + q * 4;

    const half_t* kbase = Kw + ((size_t)b * NN + w * 16 + n) * 64;
    const half_t* wb = WhJ + (size_t)b * 128 * 4096 + w * 512 + n * 32 + q * 8;

    float4 pmN  = *(const float4*)(pmr + cbase);
    float4 smN  = *(const float4*)(smr + cbase);
    int4   qmN0 = *(const int4*)(qmr + cbase * 2);
    int4   qmN1 = *(const int4*)(qmr + cbase * 2 + 4);
    half8_t ka0 = *(const half8_t*)(kbase + q * 8);
    half8_t ka1 = *(const half8_t*)(kbase + 32 + q * 8);

    f32x4 acc0 = (f32x4){0.f, 0.f, 0.f, 0.f};
    f32x4 acc1 = (f32x4){0.f, 0.f, 0.f, 0.f};
    float lacc = 0.f;

    for (int it = 0; it < NIT; ++it) {
        half8_t bwv[8];
        #pragma unroll
        for (int kq = 0; kq < 8; ++kq)
            bwv[kq] = *(const half8_t*)(wb + (size_t)(it * 8 + kq) * 4096);

        f32x4 s4 = (f32x4){0.f, 0.f, 0.f, 0.f};
        s4 = __builtin_amdgcn_mfma_f32_16x16x32_f16(ka0, qf0, s4, 0, 0, 0);
        s4 = __builtin_amdgcn_mfma_f32_16x16x32_f16(ka1, qf1, s4, 0, 0, 0);
        if (it + 1 < NIT) {
            const half_t* kp = kbase + (size_t)(it + 1) * 128 * 64;
            ka0 = *(const half8_t*)(kp + q * 8);
            ka1 = *(const half8_t*)(kp + 32 + q * 8);
        }
        const float4 pmC = pmN; const float4 smC = smN;
        const int4 qA = qmN0;  const int4 qB = qmN1;
        if (it + 1 < NIT) {
            const int jn = (it + 1) * 128 + cbase;
            pmN  = *(const float4*)(pmr + jn);
            smN  = *(const float4*)(smr + jn);
            qmN0 = *(const int4*)(qmr + (size_t)jn * 2);
            qmN1 = *(const int4*)(qmr + (size_t)jn * 2 + 4);
        }
        const float sv0 = s4[0] + pmC.x + smC.x + qbs[qA.x * 4 + qA.y];
        const float sv1 = s4[1] + pmC.y + smC.y + qbs[qA.z * 4 + qA.w];
        const float sv2 = s4[2] + pmC.z + smC.z + qbs[qB.x * 4 + qB.y];
        const float sv3 = s4[3] + pmC.w + smC.w + qbs[qB.z * 4 + qB.w];
        const half_t h0 = (half_t)__expf(fminf(sv0, 11.f));
        const half_t h1 = (half_t)__expf(fminf(sv1, 11.f));
        const half_t h2 = (half_t)__expf(fminf(sv2, 11.f));
        const half_t h3 = (half_t)__expf(fminf(sv3, 11.f));
        half4_t aP; aP[0] = h0; aP[1] = h1; aP[2] = h2; aP[3] = h3;
        lacc += (float)h0 + (float)h1 + (float)h2 + (float)h3;
        const int pb = it & 1;
        *(half4_t*)&Pl[pb][w][lane * 4] = aP;
        asm volatile("s_waitcnt lgkmcnt(0)" ::: "memory");
        __builtin_amdgcn_s_barrier();
        asm volatile("" ::: "memory");
        #pragma unroll
        for (int kq = 0; kq < 8; ++kq) {
            const half4_t pa = *(const half4_t*)&Pl[pb][kq][lane * 4];
            half4_t blo, bhi;
            blo[0] = bwv[kq][0]; blo[1] = bwv[kq][1];
            blo[2] = bwv[kq][2]; blo[3] = bwv[kq][3];
            bhi[0] = bwv[kq][4]; bhi[1] = bwv[kq][5];
            bhi[2] = bwv[kq][6]; bhi[3] = bwv[kq][7];
            acc0 = __builtin_amdgcn_mfma_f32_16x16x16f16(pa, blo, acc0, 0, 0, 0);
            acc1 = __builtin_amdgcn_mfma_f32_16x16x16f16(pa, bhi, acc1, 0, 0, 0);
        }
    }

    lacc += __shfl_xor(lacc, 16);
    lacc += __shfl_xor(lacc, 32);
    if (lane < 16) Lp[w][lane] = lacc;

    *(f32x4*)&BufT0[w * 32 + n][q * 4]      = acc0;
    *(f32x4*)&BufT0[w * 32 + 16 + n][q * 4] = acc1;
    __syncthreads();

    {
        const int r0 = 2 * w, r1 = 2 * w + 1;
        float pacc0 = 0.f, pacc1 = 0.f;
        #pragma unroll 8
        for (int c = 0; c < CDIM; ++c) {
            const float wv = op[c * 64 + lane];
            pacc0 += BufT0[c][r0] * wv;
            pacc1 += BufT0[c][r1] * wv;
        }
        float lt0 = 0.f, lt1 = 0.f;
        #pragma unroll
        for (int gg = 0; gg < 8; ++gg) { lt0 += Lp[gg][r0]; lt1 += Lp[gg][r1]; }
        float x0 = pacc0 / lt0;
        float x1 = pacc1 / lt1;
        x0 = x0 > 0.f ? x0 : (__expf(x0) - 1.f);
        x1 = x1 > 0.f ? x1 : (__expf(x1) - 1.f);
        out[((size_t)b * NN + i0 + r0) * 64 + lane] = x0;
        out[((size_t)b * NN + i0 + r1) * 64 + lane] = x1;
    }
}

// ---------------------------------------------------------------------------
extern "C" void kernel_launch(void* const* d_in, const int* in_sizes, int n_in,
                              void* d_out, int out_size, void* d_ws, size_t ws_size,
                              hipStream_t stream) {
    (void)in_sizes; (void)n_in; (void)out_size;
    const float* h  = (const float*)d_in[0];
    const float* pm = (const float*)d_in[1];
    const float* sm = (const float*)d_in[2];
    const float* W  = (const float*)d_in[3];
    const float* R  = (const float*)d_in[4];
    const float* aq = (const float*)d_in[5];
    const float* ak = (const float*)d_in[6];
    const float* qb = (const float*)d_in[7];
    const float* op = (const float*)d_in[8];
    const int*   qm = (const int*)d_in[9];
    float* out = (float*)d_out;

    half_t* ws  = (half_t*)d_ws;
    half_t* Qw  = ws;                                 // 1 MB
    half_t* Kw  = ws + (size_t)BB * NN * 64;          // 1 MB
    half_t* WhJ = ws + (size_t)BB * NN * 64 * 2;      // 4 MB
    unsigned short* bf =
        (unsigned short*)(ws + (size_t)BB * NN * 64 * 2 + (size_t)BB * NN * CDIM); // 33.5 MB

    const size_t need = ((size_t)BB * NN * 64 * 2 + (size_t)BB * NN * CDIM) * sizeof(half_t)
                      + (size_t)BB * NN * NN * sizeof(unsigned short);

    precompute_kernel<<<BB * NN / 8, 256, 0, stream>>>(h, W, R, aq, ak, Qw, Kw, WhJ);
    if (ws_size >= need) {
        fuse_bias_kernel<<<2048, 256, 0, stream>>>(pm, sm, qm, qb, bf);
        attn7_kernel<<<BB * (NN / 16), 512, 0, stream>>>(Qw, Kw, WhJ, bf, op, out);
    } else {
        attn7f_kernel<<<BB * (NN / 16), 512, 0, stream>>>(Qw, Kw, WhJ, pm, sm, qm, qb, op, out);
    }
}